// Round 2
// baseline (91.682 us; speedup 1.0000x reference)
//
#include <hip/hip_runtime.h>
#include <math.h>

#define IMG_OUT 64
#define NZ 128          // internal z resolution
#define NF 64           // internal freq channels
#define BAND 16         // evaluated channels per (pixel,z), centered at f0
#define ACC_STRIDE 80   // 64 + 16: consecutive pixel rows shifted 16 banks
#define L_CUT 9.0f      // intensity cutoff exponent for z-window

__global__ __launch_bounds__(128) void cube_sim_kernel(
    const float* __restrict__ freqs,
    const float* __restrict__ p_incl,
    const float* __restrict__ p_rot,
    const float* __restrict__ p_lb,
    const float* __restrict__ p_vshift,
    const float* __restrict__ p_vmax,
    const float* __restrict__ p_rturn,
    const float* __restrict__ p_i0,
    const float* __restrict__ p_rd,
    const float* __restrict__ p_hz,
    float* __restrict__ out)
{
    const int t  = threadIdx.x;   // 0..127 (2 waves)
    const int xo = blockIdx.x;
    const int yo = blockIdx.y;

    __shared__ float4 s_pt[NZ * 4];          // per (iz, pixel): {W, A, f0m8 bits, 0}
    __shared__ float  s_acc[4 * ACC_STRIDE]; // per-pixel fine spectra
    __shared__ int    s_zlo, s_zhi;

    // ---- init ----
    if (t == 0) { s_zlo = NZ; s_zhi = -1; }
    for (int i = t; i < 4 * ACC_STRIDE; i += 128) s_acc[i] = 0.0f;

    // ---- scalars ----
    const float incl   = p_incl[0];
    const float rot    = p_rot[0];
    const float lb     = p_lb[0];
    const float vshift = p_vshift[0];
    const float vmax   = p_vmax[0];
    const float rturn  = p_rturn[0];
    const float i0     = p_i0[0];
    const float rd     = p_rd[0];
    const float hz     = p_hz[0];

    const float LOG2E = 1.4426950408889634f;
    const float ci = cosf(incl), si = sinf(incl);
    const float cr = cosf(rot),  sr = sinf(rot);

    const float C_KMS = 299792.458f;
    const float F0    = 230.538f;
    const float f_lo  = freqs[0];
    const float df    = (freqs[15] - f_lo) * (1.0f / 63.0f);
    const float beta  = C_KMS * df / F0;                       // km/s per fine channel
    // vel label(f) = alpha - beta*f, with systemic shift folded in
    const float alpha = C_KMS * (F0 - f_lo + 2.0f * df) / F0 - vshift;
    const float inv_beta = 1.0f / beta;

    const float sgs   = sqrtf(LOG2E) / lb;     // d' = d * sgs -> G = exp2(-d'^2)
    const float negbp = -beta * sgs;
    const float Athr  = -L_CUT * LOG2E;

    const float step = 2000.0f / 127.0f;
    const float inv_rturn = 1.0f / rturn;
    const float inv_rd = 1.0f / rd;
    const float inv_hz = 1.0f / hz;
    const float two_over_pi = 0.636619772367581f;

    __syncthreads();   // acc + zlo/zhi initialized

    // ---- phase 1: per (iz = t, pixel p): W, A(log2 intensity), f0 ----
    {
        const float z  = -1000.0f + (float)t * step;
        const float x0 = -1000.0f + (float)(2 * xo) * step, x1 = x0 + step;
        const float y0 = -1000.0f + (float)(2 * yo) * step, y1 = y0 + step;
        float amax = -1e30f;
        #pragma unroll
        for (int p = 0; p < 4; ++p) {
            const float x = (p >> 1) ? x1 : x0;
            const float y = (p & 1) ? y1 : y0;
            const float rx = cr * x - sr * y;
            const float u  = sr * x + cr * y;
            const float ry = ci * u - si * z;
            const float rz = si * u + ci * z;
            const float r2 = rx * rx + ry * ry + 1e-12f;
            const float inv_rad = __builtin_amdgcn_rsqf(r2);
            const float rad = r2 * inv_rad;
            const float v_abs = vmax * two_over_pi * atanf(rad * inv_rturn);
            const float v = -si * v_abs * rx * inv_rad;          // v_los
            const float A = (-rad * inv_rd - fabsf(rz) * inv_hz) * LOG2E;
            int f0 = (int)rintf((alpha - v) * inv_beta);
            f0 = min(max(f0, 8), 56);                            // keep band in [0,63]
            const float W = sgs * (alpha - beta * (float)(f0 - 8) - v);
            s_pt[t * 4 + p] = make_float4(W, A, __int_as_float(f0 - 8), 0.0f);
            amax = fmaxf(amax, A);
        }
        if (amax >= Athr) { atomicMin(&s_zlo, t); atomicMax(&s_zhi, t); }
    }
    __syncthreads();

    // ---- phase 2: band KDE scatter ----
    const int wid  = t >> 6;
    const int lane = t & 63;
    const int p    = lane >> 4;
    const float bf = (float)(lane & 15);
    const int   Cb = p * ACC_STRIDE + (lane & 15);
    const int zlo = s_zlo, zhi = s_zhi;

    #pragma unroll 4
    for (int iz = zlo + wid; iz <= zhi; iz += 2) {
        const float4 q = s_pt[iz * 4 + p];
        const int idx = Cb + __float_as_int(q.z);
        const float d = fmaf(negbp, bf, q.x);    // d' = W - beta'*b
        const float w = fmaf(-d, d, q.y);        // A - d'^2
        atomicAdd(&s_acc[idx], __builtin_amdgcn_exp2f(w));   // I*G
    }
    __syncthreads();

    // ---- phase 3: pool 4 pixels x 4 sub-channels ----
    if (t < 16) {
        float s = 0.0f;
        #pragma unroll
        for (int pp = 0; pp < 4; ++pp) {
            const float4 v4 = *(const float4*)&s_acc[pp * ACC_STRIDE + 4 * t];
            s += (v4.x + v4.y) + (v4.z + v4.w);
        }
        const float scale = i0 * 0.0625f / sqrtf(6.283185307179586f * lb * lb);
        out[t * (IMG_OUT * IMG_OUT) + xo * IMG_OUT + yo] = s * scale;
    }
}

extern "C" void kernel_launch(void* const* d_in, const int* in_sizes, int n_in,
                              void* d_out, int out_size, void* d_ws, size_t ws_size,
                              hipStream_t stream) {
    (void)in_sizes; (void)n_in; (void)d_ws; (void)ws_size; (void)out_size;
    const float* freqs  = (const float*)d_in[0];
    const float* incl   = (const float*)d_in[1];
    const float* rot    = (const float*)d_in[2];
    const float* lb     = (const float*)d_in[3];
    const float* vshift = (const float*)d_in[4];
    const float* vmax   = (const float*)d_in[5];
    const float* rturn  = (const float*)d_in[6];
    const float* i0     = (const float*)d_in[7];
    const float* rd     = (const float*)d_in[8];
    const float* hz     = (const float*)d_in[9];
    float* out = (float*)d_out;

    dim3 grid(IMG_OUT, IMG_OUT);
    dim3 block(128);
    hipLaunchKernelGGL(cube_sim_kernel, grid, block, 0, stream,
                       freqs, incl, rot, lb, vshift, vmax, rturn, i0, rd, hz, out);
}